// Round 4
// baseline (343.595 us; speedup 1.0000x reference)
//
#include <hip/hip_runtime.h>

// Problem constants (fixed by the reference): E=8, M=32768, K=1024, N=1024
#define M_DIM 32768
#define K_DIM 1024
#define N_DIM 1024
#define E_NUM 8

#define BM 128
#define BN 128
#define BK 128            // k-bytes staged per step (full 128B cache lines)
#define KSTEPS (K_DIM / BK)   // 8

typedef __attribute__((ext_vector_type(4))) int v4i;

// ---------------------------------------------------------------------------
// Pass 1 (merged): blocks [0, 8192) pack x; blocks [8192, 8704) pack+transpose
// weight. Uniform branch per block.
//   pack_x: [M][K] int32 -> int8, 64B in / 16B out per thread.
//   pack_wt: [E][K][N] int32 -> [E][N][K] int8, 64n x 256k tile per block;
//            loads 256B/wave contiguous, stores 256B/wave contiguous.
// ---------------------------------------------------------------------------
__global__ __launch_bounds__(256) void pack_kernel(const int4* __restrict__ x,
                                                   int4* __restrict__ xq,
                                                   const int* __restrict__ w,
                                                   int* __restrict__ wt) {
    __shared__ signed char tile[64][260];   // only used by pack_wt blocks
    const int tid = threadIdx.x;

    if (blockIdx.x < 8192) {
        const int i = blockIdx.x * 256 + tid;
        int4 a = x[i * 4 + 0], b = x[i * 4 + 1], c = x[i * 4 + 2], d = x[i * 4 + 3];
        int4 o;
        o.x = (a.x & 255) | ((a.y & 255) << 8) | ((a.z & 255) << 16) | (a.w << 24);
        o.y = (b.x & 255) | ((b.y & 255) << 8) | ((b.z & 255) << 16) | (b.w << 24);
        o.z = (c.x & 255) | ((c.y & 255) << 8) | ((c.z & 255) << 16) | (c.w << 24);
        o.w = (d.x & 255) | ((d.y & 255) << 8) | ((d.z & 255) << 16) | (d.w << 24);
        xq[i] = o;
        return;
    }

    const int b    = blockIdx.x - 8192;     // 0..511
    const int e    = b >> 6;                // 0..7
    const int k0   = ((b >> 4) & 3) * 256;
    const int n0   = (b & 15) * 64;
    const int lane = tid & 63;
    const int wv   = tid >> 6;

    const int* wp = w + ((size_t)e << 20);
#pragma unroll 4
    for (int i = 0; i < 64; ++i) {
        const int k = wv * 64 + i;          // each wave: 64 k-rows
        tile[lane][k] = (signed char)wp[(size_t)(k0 + k) * N_DIM + n0 + lane];
    }
    __syncthreads();

    int* wo = wt + ((size_t)e << 18);       // int units: 1MB/4 per expert
#pragma unroll
    for (int i = 0; i < 16; ++i) {
        const int n = i * 4 + wv;
        const int v = *(const int*)&tile[n][lane * 4];
        wo[(size_t)(n0 + n) * (K_DIM / 4) + (k0 >> 2) + lane] = v;
    }
}

// ---------------------------------------------------------------------------
// Pass 2: grouped int8 GEMM + fused dequant.
// BK=128 full-line staging, double-buffered LDS (2x32KB), issue-early
// prefetch, XOR-swizzled k-slots (verified R3: SQ_LDS_BANK_CONFLICT == 0).
// NEW (R4): LDS-bounce epilogue -- acc is dequantized into a 128x128 fp32
// tile in the (reused) staging LDS, then streamed out as full 512B rows so
// every HBM write is a full cache line (R3 showed +45MB WRITE / +~26MB FETCH
// from half-line RMW stores).
// XCD swizzle: gid&7 = n-tile -> each XCD keeps its 1MB B-slice L2-resident.
// group_list dtype sniffed (int32 vs int64) via g32[7] == M.
// ---------------------------------------------------------------------------
__global__ __launch_bounds__(256, 2) void gmm_kernel(
    const signed char* __restrict__ xq,    // [M][K] int8
    const signed char* __restrict__ wtq,   // [E][N][K] int8
    const float* __restrict__ scale,       // [E][N]
    const float* __restrict__ pts,         // [M]
    const int* __restrict__ g32,           // group_list viewed as int32
    float* __restrict__ out)               // [M][N] fp32
{
    __shared__ signed char smem[4 * BM * BK];   // 64 KB: As[2] | Bs[2]
    signed char* As = smem;                     // As[b] = smem + b*16KB
    signed char* Bs = smem + 2 * BM * BK;       // Bs[b] = ... + b*16KB
    float* obuf = (float*)smem;                 // reused for epilogue: [128][128]

    const int tid  = threadIdx.x;
    const int lane = tid & 63;
    const int wv   = tid >> 6;             // wave 0..3
    const int gid  = blockIdx.x;
    const int m0   = (gid >> 3) * BM;
    const int n0   = (gid & 7) * BN;

    // group_list (dtype-robust)
    const bool g_is_i64 = (g32[7] != M_DIM);
    int cum[E_NUM];
#pragma unroll
    for (int e = 0; e < E_NUM; ++e)
        cum[e] = g_is_i64 ? g32[2 * e] : g32[e];
    int e0 = 0;
    while (e0 < E_NUM - 1 && cum[e0] <= m0) ++e0;
    int e1 = 0;
    while (e1 < E_NUM - 1 && cum[e1] <= m0 + BM - 1) ++e1;

    const int wm    = (wv >> 1) * 64;
    const int wn    = (wv & 1) * 64;
    const int row_a = lane & 15;
    const int quad  = lane >> 4;
    const int rx    = row_a & 7;

    // staging lane geometry: chunk = 8 rows x 128B = 1KB
    const int st_r = lane >> 3;                     // row in chunk 0..7
    const int st_c = ((lane & 7) ^ st_r) * 16;      // swizzled col bytes

    const signed char* xg = xq + (size_t)m0 * K_DIM;

    for (int e = e0; e <= e1; ++e) {
        const int lo = (e == 0) ? 0 : cum[e - 1];
        const int hi = cum[e];
        if (hi <= lo) continue;            // block-uniform
        const int slo = lo > m0 ? lo : m0;
        const int shi = hi < m0 + BM ? hi : m0 + BM;
        if (slo >= shi) continue;

        const signed char* wg = wtq + ((size_t)e << 20) + (size_t)n0 * K_DIM;

        // prefetch epilogue scalars (fly during the whole GEMM)
        float sc[4], pt[16];
#pragma unroll
        for (int j = 0; j < 4; ++j)
            sc[j] = scale[e * N_DIM + n0 + wn + j * 16 + row_a];
#pragma unroll
        for (int i = 0; i < 4; ++i)
#pragma unroll
            for (int r = 0; r < 4; ++r)
                pt[i * 4 + r] = pts[m0 + wm + i * 16 + quad * 4 + r];

        v4i acc[4][4];
#pragma unroll
        for (int i = 0; i < 4; ++i)
#pragma unroll
            for (int j = 0; j < 4; ++j)
                acc[i][j] = (v4i){0, 0, 0, 0};

        auto stage = [&](int t, int b) {
            const int kb = t * BK;
#pragma unroll
            for (int s = 0; s < 4; ++s) {
                const int c   = s * 4 + wv;        // chunk 0..15
                const int row = c * 8 + st_r;      // 0..127
                __builtin_amdgcn_global_load_lds(
                    (const __attribute__((address_space(1))) void*)
                        (xg + (size_t)row * K_DIM + kb + st_c),
                    (__attribute__((address_space(3))) void*)(As + b * BM * BK + c * 1024),
                    16, 0, 0);
                __builtin_amdgcn_global_load_lds(
                    (const __attribute__((address_space(1))) void*)
                        (wg + (size_t)row * K_DIM + kb + st_c),
                    (__attribute__((address_space(3))) void*)(Bs + b * BM * BK + c * 1024),
                    16, 0, 0);
            }
        };

        stage(0, 0);
        __syncthreads();

        for (int t = 0; t < KSTEPS; ++t) {
            const int cur = t & 1;
            if (t + 1 < KSTEPS) stage(t + 1, cur ^ 1);   // issue, don't wait

#pragma unroll
            for (int w = 0; w < 2; ++w) {                // two K=64 windows
                const int sa = ((w << 2) + quad) ^ rx;   // swizzled 16B slot
                v4i af[4], bf[4];
#pragma unroll
                for (int i = 0; i < 4; ++i)
                    af[i] = *(const v4i*)(As + cur * BM * BK + (wm + i * 16 + row_a) * BK + sa * 16);
#pragma unroll
                for (int j = 0; j < 4; ++j)
                    bf[j] = *(const v4i*)(Bs + cur * BM * BK + (wn + j * 16 + row_a) * BK + sa * 16);
#pragma unroll
                for (int i = 0; i < 4; ++i)
#pragma unroll
                    for (int j = 0; j < 4; ++j)
                        acc[i][j] = __builtin_amdgcn_mfma_i32_16x16x64_i8(
                            af[i], bf[j], acc[i][j], 0, 0, 0);
            }
            __syncthreads();    // drains the t+1 prefetch -- after compute
        }

        // ---- epilogue: dequant into LDS tile, stream out full lines ----
#pragma unroll
        for (int i = 0; i < 4; ++i)
#pragma unroll
            for (int j = 0; j < 4; ++j)
#pragma unroll
                for (int r = 0; r < 4; ++r)
                    obuf[(wm + i * 16 + quad * 4 + r) * BN + wn + j * 16 + row_a] =
                        (float)acc[i][j][r] * sc[j] * pt[i * 4 + r];
        __syncthreads();

        const int c4 = (tid & 31) * 4;          // float offset within row
        const int r8 = tid >> 5;                // 0..7
#pragma unroll
        for (int it = 0; it < 16; ++it) {
            const int row = it * 8 + r8;        // 0..127
            const int rr  = m0 + row;
            if (rr >= slo && rr < shi)
                *(float4*)(out + (size_t)rr * N_DIM + n0 + c4) =
                    *(const float4*)(obuf + row * BN + c4);
        }
        __syncthreads();    // protect LDS before next expert's stage(0,0)
    }
}

// ---------------------------------------------------------------------------
extern "C" void kernel_launch(void* const* d_in, const int* in_sizes, int n_in,
                              void* d_out, int out_size, void* d_ws, size_t ws_size,
                              hipStream_t stream) {
    const int*   x     = (const int*)d_in[0];
    const int*   w     = (const int*)d_in[1];
    const float* scale = (const float*)d_in[2];
    const float* pts   = (const float*)d_in[3];
    const int*   g32   = (const int*)d_in[4];   // int32 or int64 -- sniffed in-kernel
    float*       out   = (float*)d_out;

    signed char* xq  = (signed char*)d_ws;                 // 32 MB
    signed char* wtq = xq + (size_t)M_DIM * K_DIM;         // 8 MB

    pack_kernel<<<8192 + 512, 256, 0, stream>>>(
        (const int4*)x, (int4*)xq, w, (int*)wtq);

    gmm_kernel<<<(M_DIM / BM) * (N_DIM / BN), 256, 0, stream>>>(
        xq, wtq, scale, pts, g32, out);
}